// Round 9
// baseline (52.656 us; speedup 1.0000x reference)
//
#include <hip/hip_runtime.h>

#define BATCH 32
#define SS 1024
#define NSTEPS 972
#define LSTR 20                     // floats per lane row: 16 data + 4 pad = 80B (16B-aligned, 8-way bank spread)

#define UNVIS   0x7F000000u         // huge finite float sentinels: UNVIS < CLOSED < OBST, all > any real f
#define CLOSEDB 0x7F000001u
#define OBSTB   0x7F000002u

typedef unsigned long long ull;

template <int CTRL>
__device__ __forceinline__ int dpp32(int v) {
    return __builtin_amdgcn_update_dpp(v, v, CTRL, 0xF, 0xF, false);
}

// 64-lane f32 min, result (bit-exact copy of some input) broadcast from lane 63.
__device__ __forceinline__ float wave_min_f32_bcast(float v) {
    float t;
    t = __int_as_float(dpp32<0xB1 >(__float_as_int(v))); v = fminf(v, t);  // quad xor1
    t = __int_as_float(dpp32<0x4E >(__float_as_int(v))); v = fminf(v, t);  // quad xor2
    t = __int_as_float(dpp32<0x141>(__float_as_int(v))); v = fminf(v, t);  // row_half_mirror
    t = __int_as_float(dpp32<0x140>(__float_as_int(v))); v = fminf(v, t);  // row_mirror
    t = __int_as_float(dpp32<0x142>(__float_as_int(v))); v = fminf(v, t);  // row_bcast15
    t = __int_as_float(dpp32<0x143>(__float_as_int(v))); v = fminf(v, t);  // row_bcast31
    return __int_as_float(__builtin_amdgcn_readlane(__float_as_int(v), 63));
}

template <int CTRL>
__device__ __forceinline__ ull dpp64(ull k) {
    unsigned lo = (unsigned)dpp32<CTRL>((int)(unsigned)k);
    unsigned hi = (unsigned)dpp32<CTRL>((int)(unsigned)(k >> 32));
    return ((ull)hi << 32) | lo;
}

// u64 min within each 8-lane group (lanes 0-7 hold the relax keys).
__device__ __forceinline__ ull grp8_min_u64(ull k) {
    ull t;
    t = dpp64<0xB1 >(k); k = t < k ? t : k;
    t = dpp64<0x4E >(k); k = t < k ? t : k;
    t = dpp64<0x141>(k); k = t < k ? t : k;
    return k;
}

__device__ __forceinline__ unsigned umin2(unsigned a, unsigned b) { return a < b ? a : b; }
__device__ __forceinline__ unsigned slotc(float v, unsigned lm, unsigned i) {
    return (__float_as_uint(v) == lm) ? i : 63u;   // lane-local slot candidate
}

__global__ __launch_bounds__(64)
void astar_kernel(const float* __restrict__ start_maps,
                  const float* __restrict__ goal_maps,
                  const float* __restrict__ obst_maps,
                  float* __restrict__ out)
{
    const int b = blockIdx.x;
    const int lane = threadIdx.x;

    __shared__ __align__(16) float fop[64 * LSTR];   // padded: cell c at (c>>4)*LSTR + (c&15)
    __shared__ __align__(16) float g_s[SS];
    __shared__ __align__(16) float fh_s[SS];         // 0.501f * h
    __shared__ unsigned short par_s[SS];
    __shared__ int sh_start, sh_goal;

    const float* st = start_maps + b * SS;
    const float* gl = goal_maps + b * SS;
    const float* ob = obst_maps + b * SS;

    for (int i = 0; i < 16; ++i) {
        int c = i * 64 + lane;
        if (st[c] > 0.5f) sh_start = c;
        if (gl[c] > 0.5f) sh_goal = c;
    }
    __syncthreads();
    const int start_idx = sh_start;
    const int goal_idx = sh_goal;
    const float gi = (float)(goal_idx >> 5);
    const float gj = (float)(goal_idx & 31);
    const float SQRT2F = 1.41421356237309515f;   // fl32(sqrt(2))
    const float WH = 0.501f;

    for (int i = 0; i < 16; ++i) {
        int c = i * 64 + lane;
        float dx = fabsf((float)(c >> 5) - gi);
        float dy = fabsf((float)(c & 31) - gj);
        float h = __fadd_rn(__fmul_rn(fminf(dx, dy), SQRT2F), fabsf(dx - dy));
        fh_s[c] = __fmul_rn(WH, h);
        g_s[c] = 0.0f;
        par_s[c] = (unsigned short)goal_idx;
        fop[(c >> 4) * LSTR + (c & 15)] = __uint_as_float(ob[c] > 0.5f ? UNVIS : OBSTB);
    }
    __syncthreads();
    if (lane == 0)
        fop[(start_idx >> 4) * LSTR + (start_idx & 15)] = fh_s[start_idx];  // f = fl(0.5*0 + fh) = fh
    __syncthreads();

    const float* frow = &fop[lane * LSTR];

    // ---- pipeline state ----
    float4 A0, A1, A2, A3, B0, B1, B2, B3;
    B0 = *(const float4*)(frow + 0);
    B1 = *(const float4*)(frow + 4);
    B2 = *(const float4*)(frow + 8);
    B3 = *(const float4*)(frow + 12);
    A0 = B0; A1 = B1; A2 = B2; A3 = B3;     // A overwritten at end of iter 0; init only
    ull nk = ~0ull;                          // carried: last relax keys (lanes 0-7)
    ull skey = 0;                            // carried: stale argmin key for the NEXT step
    bool solved = false;

    // stale key = argmin over a bank with cell `psel` patched out; key=(fbits<<10)|cell
    auto stale_key = [&](float4& q0, float4& q1, float4& q2, float4& q3, int psel) -> ull {
        const float CB = __uint_as_float(CLOSEDB);
        int po = psel >> 4, ps = psel & 15;
        bool own = (lane == po);
        q0.x = (own && ps == 0 ) ? CB : q0.x;  q0.y = (own && ps == 1 ) ? CB : q0.y;
        q0.z = (own && ps == 2 ) ? CB : q0.z;  q0.w = (own && ps == 3 ) ? CB : q0.w;
        q1.x = (own && ps == 4 ) ? CB : q1.x;  q1.y = (own && ps == 5 ) ? CB : q1.y;
        q1.z = (own && ps == 6 ) ? CB : q1.z;  q1.w = (own && ps == 7 ) ? CB : q1.w;
        q2.x = (own && ps == 8 ) ? CB : q2.x;  q2.y = (own && ps == 9 ) ? CB : q2.y;
        q2.z = (own && ps == 10) ? CB : q2.z;  q2.w = (own && ps == 11) ? CB : q2.w;
        q3.x = (own && ps == 12) ? CB : q3.x;  q3.y = (own && ps == 13) ? CB : q3.y;
        q3.z = (own && ps == 14) ? CB : q3.z;  q3.w = (own && ps == 15) ? CB : q3.w;
        float a0 = fminf(fminf(q0.x, q0.y), fminf(q0.z, q0.w));
        float a1 = fminf(fminf(q1.x, q1.y), fminf(q1.z, q1.w));
        float a2 = fminf(fminf(q2.x, q2.y), fminf(q2.z, q2.w));
        float a3 = fminf(fminf(q3.x, q3.y), fminf(q3.z, q3.w));
        float lmin = fminf(fminf(a0, a1), fminf(a2, a3));
        unsigned lm = __float_as_uint(lmin);
        unsigned s0 = umin2(umin2(slotc(q0.x, lm, 0),  slotc(q0.y, lm, 1)),
                            umin2(slotc(q0.z, lm, 2),  slotc(q0.w, lm, 3)));
        unsigned s1 = umin2(umin2(slotc(q1.x, lm, 4),  slotc(q1.y, lm, 5)),
                            umin2(slotc(q1.z, lm, 6),  slotc(q1.w, lm, 7)));
        unsigned s2 = umin2(umin2(slotc(q2.x, lm, 8),  slotc(q2.y, lm, 9)),
                            umin2(slotc(q2.z, lm, 10), slotc(q2.w, lm, 11)));
        unsigned s3 = umin2(umin2(slotc(q3.x, lm, 12), slotc(q3.y, lm, 13)),
                            umin2(slotc(q3.z, lm, 14), slotc(q3.w, lm, 15)));
        unsigned slot = umin2(umin2(s0, s1), umin2(s2, s3));
        float gmin = wave_min_f32_bcast(lmin);
        ull bal = __ballot(lm == __float_as_uint(gmin));
        int owner = (int)__builtin_ctzll(bal);
        int cell = owner * 16 + __builtin_amdgcn_readlane((int)slot, owner);
        return (((ull)__float_as_uint(gmin)) << 10) | (unsigned)cell;
    };

    // bootstrap: selection key for step 0 over the initial state (no patch: psel out of range)
    skey = stale_key(B0, B1, B2, B3, 0x7FFF);

    // one A* step. tree bank holds S_{t-1} (to build next step's stale key);
    // load bank receives S_t at the end.
    auto STEP = [&](float4& t0, float4& t1, float4& t2, float4& t3,
                    float4& l0, float4& l1, float4& l2, float4& l3)
    {
        // fresh key from last step's relax (strictly dominates its stale copies)
        ull red = grp8_min_u64(nk);
        unsigned frlo = (unsigned)__builtin_amdgcn_readlane((int)(unsigned)red, 0);
        unsigned frhi = (unsigned)__builtin_amdgcn_readlane((int)(unsigned)(red >> 32), 0);
        ull fkey = ((ull)frhi << 32) | frlo;
        ull key = fkey < skey ? fkey : skey;     // u64 order = (f asc, idx asc)
        const int sel = (int)(key & 1023ull);
        solved = (sel == goal_idx);
        const int si = sel >> 5, sj = sel & 31;

        // close sel (neighbors never alias sel)
        if (lane == 0)
            fop[(sel >> 4) * LSTR + (sel & 15)] = __uint_as_float(CLOSEDB);

        // relax input reads, ALL 64 lanes (idle lanes read safe dummy addr = sel)
        // -> loads issue here, wait sinks below the stale tree
        int k8 = lane < 8 ? (lane < 4 ? lane : lane + 1) : 4;
        int di = k8 / 3 - 1;
        int dj = k8 - (k8 / 3) * 3 - 1;
        int ni = si + di, nj = sj + dj;
        bool act = (lane < 8) && ((unsigned)ni < 32u) && ((unsigned)nj < 32u);
        int nb = act ? ni * 32 + nj : sel;
        int fa = (nb >> 4) * LSTR + (nb & 15);
        unsigned fbv = __float_as_uint(fop[fa]);
        float gnb = g_s[nb];
        float fhn = fh_s[nb];
        float gsel = g_s[sel];

        // ---- next step's stale key: pure VALU, overlaps the LDS wait above ----
        skey = stale_key(t0, t1, t2, t3, sel);

        // ---- relax compute + writes ----
        nk = ~0ull;
        float w = ((di != 0) && (dj != 0)) ? SQRT2F : 1.0f;
        float g2 = __fadd_rn(gsel, w);               // exact: fl(g_sel + w)
        bool rel = act && ((fbv == UNVIS) || (fbv < UNVIS && gnb > g2));
        if (rel) {
            float fnew = __fadd_rn(__fmul_rn(0.5f, g2), fhn);
            fop[fa] = fnew;
            g_s[nb] = g2;
            par_s[nb] = (unsigned short)sel;
            nk = (((ull)__float_as_uint(fnew)) << 10) | (unsigned)nb;
        }
        asm volatile("" ::: "memory");
        // capture S_t for use two steps ahead (in-order DS: sees close + relaxes)
        l0 = *(const float4*)(frow + 0);
        l1 = *(const float4*)(frow + 4);
        l2 = *(const float4*)(frow + 8);
        l3 = *(const float4*)(frow + 12);
        asm volatile("" ::: "memory");
    };

    #pragma unroll 1
    for (int t = 0; t < NSTEPS; t += 2) {
        STEP(B0, B1, B2, B3, A0, A1, A2, A3);   // tree on S_{t-1} (B), loads -> A = S_t
        if (solved) break;
        STEP(A0, A1, A2, A3, B0, B1, B2, B3);   // tree on S_t (A), loads -> B = S_{t+1}
        if (solved) break;
    }

    float* out_hist = out + b * SS;
    float* out_path = out + BATCH * SS + b * SS;
    float* out_g    = out + 2 * BATCH * SS + b * SS;
    for (int i = 0; i < 16; ++i) {
        int c = i * 64 + lane;
        unsigned fbv = __float_as_uint(fop[(c >> 4) * LSTR + (c & 15)]);
        out_hist[c] = (fbv == CLOSEDB) ? 1.0f : 0.0f;
        out_g[c]    = g_s[c];
        out_path[c] = (c == goal_idx) ? 1.0f : 0.0f;
    }
    __syncthreads();   // drain stores before backtrack overwrites
    if (lane == 0) {
        int loc = par_s[goal_idx];
        for (int it = 0; it < NSTEPS; ++it) {
            out_path[loc] = 1.0f;
            if (loc == goal_idx) break;   // parent chain strictly decreasing in expansion time
            loc = par_s[loc];
        }
    }
}

extern "C" void kernel_launch(void* const* d_in, const int* in_sizes, int n_in,
                              void* d_out, int out_size, void* d_ws, size_t ws_size,
                              hipStream_t stream)
{
    // d_in: [0]=cost_maps (unused in 'default' mode), [1]=start, [2]=goal, [3]=obstacles
    const float* start_maps = (const float*)d_in[1];
    const float* goal_maps  = (const float*)d_in[2];
    const float* obst_maps  = (const float*)d_in[3];
    float* out = (float*)d_out;
    hipLaunchKernelGGL(astar_kernel, dim3(BATCH), dim3(64), 0, stream,
                       start_maps, goal_maps, obst_maps, out);
}

// Round 10
// 52.436 us; speedup vs baseline: 1.0042x; 1.0042x over previous
//
#include <hip/hip_runtime.h>

#define BATCH 32
#define SS 1024
#define NSTEPS 972
#define LSTR 20                     // floats per lane row: 16 data + 4 pad = 80B (16B-aligned, 8-way bank spread)

#define UNVIS   0x7F000000u         // huge finite float sentinels: UNVIS < CLOSED < OBST, all > any real f
#define CLOSEDB 0x7F000001u
#define OBSTB   0x7F000002u

typedef unsigned long long ull;

template <int CTRL>
__device__ __forceinline__ int dpp32(int v) {
    return __builtin_amdgcn_update_dpp(v, v, CTRL, 0xF, 0xF, false);
}

// 64-lane f32 min, result (bit-exact copy of some input) broadcast from lane 63.
__device__ __forceinline__ float wave_min_f32_bcast(float v) {
    float t;
    t = __int_as_float(dpp32<0xB1 >(__float_as_int(v))); v = fminf(v, t);  // quad xor1
    t = __int_as_float(dpp32<0x4E >(__float_as_int(v))); v = fminf(v, t);  // quad xor2
    t = __int_as_float(dpp32<0x141>(__float_as_int(v))); v = fminf(v, t);  // row_half_mirror
    t = __int_as_float(dpp32<0x140>(__float_as_int(v))); v = fminf(v, t);  // row_mirror
    t = __int_as_float(dpp32<0x142>(__float_as_int(v))); v = fminf(v, t);  // row_bcast15
    t = __int_as_float(dpp32<0x143>(__float_as_int(v))); v = fminf(v, t);  // row_bcast31
    return __int_as_float(__builtin_amdgcn_readlane(__float_as_int(v), 63));
}

// min within each 8-lane group, butterfly (every lane of the group gets the min)
__device__ __forceinline__ float grp8_min_f32(float v) {
    float t;
    t = __int_as_float(dpp32<0xB1 >(__float_as_int(v))); v = fminf(v, t);
    t = __int_as_float(dpp32<0x4E >(__float_as_int(v))); v = fminf(v, t);
    t = __int_as_float(dpp32<0x141>(__float_as_int(v))); v = fminf(v, t);
    return v;
}

__device__ __forceinline__ unsigned umin2(unsigned a, unsigned b) { return a < b ? a : b; }
__device__ __forceinline__ unsigned slotc(float v, unsigned lm, unsigned i) {
    return (__float_as_uint(v) == lm) ? i : 63u;   // lane-local slot candidate
}

__global__ __launch_bounds__(64)
void astar_kernel(const float* __restrict__ start_maps,
                  const float* __restrict__ goal_maps,
                  const float* __restrict__ obst_maps,
                  float* __restrict__ out)
{
    const int b = blockIdx.x;
    const int lane = threadIdx.x;

    __shared__ __align__(16) float fop[64 * LSTR];   // padded: cell c at (c>>4)*LSTR + (c&15)
    __shared__ __align__(16) float g_s[SS];
    __shared__ __align__(16) float fh_s[SS];         // 0.501f * h
    __shared__ unsigned short par_s[SS];
    __shared__ int sh_start, sh_goal;

    const float* st = start_maps + b * SS;
    const float* gl = goal_maps + b * SS;
    const float* ob = obst_maps + b * SS;

    for (int i = 0; i < 16; ++i) {
        int c = i * 64 + lane;
        if (st[c] > 0.5f) sh_start = c;
        if (gl[c] > 0.5f) sh_goal = c;
    }
    __syncthreads();
    const int start_idx = sh_start;
    const int goal_idx = sh_goal;
    const float gi = (float)(goal_idx >> 5);
    const float gj = (float)(goal_idx & 31);
    const float SQRT2F = 1.41421356237309515f;   // fl32(sqrt(2))
    const float WH = 0.501f;

    for (int i = 0; i < 16; ++i) {
        int c = i * 64 + lane;
        float dx = fabsf((float)(c >> 5) - gi);
        float dy = fabsf((float)(c & 31) - gj);
        float h = __fadd_rn(__fmul_rn(fminf(dx, dy), SQRT2F), fabsf(dx - dy));
        fh_s[c] = __fmul_rn(WH, h);
        g_s[c] = 0.0f;
        par_s[c] = (unsigned short)goal_idx;
        fop[(c >> 4) * LSTR + (c & 15)] = __uint_as_float(ob[c] > 0.5f ? UNVIS : OBSTB);
    }
    __syncthreads();
    if (lane == 0)
        fop[(start_idx >> 4) * LSTR + (start_idx & 15)] = fh_s[start_idx];  // f = fl(0.5*0 + fh) = fh
    __syncthreads();

    const float* frow = &fop[lane * LSTR];
    // single register bank: holds S_{t-1} (state before current step's close/relax)
    float4 K0 = *(const float4*)(frow + 0);
    float4 K1 = *(const float4*)(frow + 4);
    float4 K2 = *(const float4*)(frow + 8);
    float4 K3 = *(const float4*)(frow + 12);

    const float CB = __uint_as_float(CLOSEDB);
    const float INFF = __int_as_float(0x7f800000);

    // first selection is trivially the start cell (only open cell)
    int sel = start_idx;

    #pragma unroll 1
    for (int step = 0; step < NSTEPS; ++step) {
        const bool solved = (sel == goal_idx);
        const int si = sel >> 5, sj = sel & 31;

        // ---- 1. close sel (neighbors never alias sel) ----
        if (lane == 0)
            fop[(sel >> 4) * LSTR + (sel & 15)] = __uint_as_float(CLOSEDB);
        asm volatile("" ::: "memory");

        // ---- 2. relax input reads, all 64 lanes (idle lanes read safe dummy = sel) ----
        int k8 = lane < 8 ? (lane < 4 ? lane : lane + 1) : 4;
        int di = k8 / 3 - 1;
        int dj = k8 - (k8 / 3) * 3 - 1;
        int ni = si + di, nj = sj + dj;
        bool act = (lane < 8) && ((unsigned)ni < 32u) && ((unsigned)nj < 32u);
        int nb = act ? ni * 32 + nj : sel;
        int fa = (nb >> 4) * LSTR + (nb & 15);
        unsigned fbv = __float_as_uint(fop[fa]);
        float gnb = g_s[nb];
        float fhn = fh_s[nb];
        float gsel = g_s[sel];

        // ---- 3. stale selection: argmin over bank(S_{t-1}) with sel patched CLOSED ----
        //     pure VALU on registers -> overlaps the LDS wait of step (2)
        const bool own = (lane == (sel >> 4));
        const int ps = sel & 15;
        float q00 = (own && ps == 0 ) ? CB : K0.x;  float q01 = (own && ps == 1 ) ? CB : K0.y;
        float q02 = (own && ps == 2 ) ? CB : K0.z;  float q03 = (own && ps == 3 ) ? CB : K0.w;
        float q04 = (own && ps == 4 ) ? CB : K1.x;  float q05 = (own && ps == 5 ) ? CB : K1.y;
        float q06 = (own && ps == 6 ) ? CB : K1.z;  float q07 = (own && ps == 7 ) ? CB : K1.w;
        float q08 = (own && ps == 8 ) ? CB : K2.x;  float q09 = (own && ps == 9 ) ? CB : K2.y;
        float q10 = (own && ps == 10) ? CB : K2.z;  float q11 = (own && ps == 11) ? CB : K2.w;
        float q12 = (own && ps == 12) ? CB : K3.x;  float q13 = (own && ps == 13) ? CB : K3.y;
        float q14 = (own && ps == 14) ? CB : K3.z;  float q15 = (own && ps == 15) ? CB : K3.w;
        float a0 = fminf(fminf(q00, q01), fminf(q02, q03));
        float a1 = fminf(fminf(q04, q05), fminf(q06, q07));
        float a2 = fminf(fminf(q08, q09), fminf(q10, q11));
        float a3 = fminf(fminf(q12, q13), fminf(q14, q15));
        float lmin = fminf(fminf(a0, a1), fminf(a2, a3));
        const unsigned lm = __float_as_uint(lmin);
        unsigned s0 = umin2(umin2(slotc(q00, lm, 0),  slotc(q01, lm, 1)),
                            umin2(slotc(q02, lm, 2),  slotc(q03, lm, 3)));
        unsigned s1 = umin2(umin2(slotc(q04, lm, 4),  slotc(q05, lm, 5)),
                            umin2(slotc(q06, lm, 6),  slotc(q07, lm, 7)));
        unsigned s2 = umin2(umin2(slotc(q08, lm, 8),  slotc(q09, lm, 9)),
                            umin2(slotc(q10, lm, 10), slotc(q11, lm, 11)));
        unsigned s3 = umin2(umin2(slotc(q12, lm, 12), slotc(q13, lm, 13)),
                            umin2(slotc(q14, lm, 14), slotc(q15, lm, 15)));
        unsigned slot = umin2(umin2(s0, s1), umin2(s2, s3));
        const float gmin = wave_min_f32_bcast(lmin);
        const unsigned sbits = __float_as_uint(gmin);
        const ull bal = __ballot(lm == sbits);
        const int owner = (int)__builtin_ctzll(bal);
        const unsigned scell = (unsigned)(owner * 16 + __builtin_amdgcn_readlane((int)slot, owner));

        // ---- 4. relax compute (the lgkm wait for step-2 loads lands here) ----
        float w = ((di != 0) && (dj != 0)) ? SQRT2F : 1.0f;
        float g2 = __fadd_rn(gsel, w);               // exact: fl(g_sel + w)
        bool rel = act && ((fbv == UNVIS) || (fbv < UNVIS && gnb > g2));
        float fnew = __fadd_rn(__fmul_rn(0.5f, g2), fhn);
        if (rel) fop[fa] = fnew;
        asm volatile("" ::: "memory");

        // ---- 5. bank reload: sees close + relax fop writes -> S_t; lands before
        //         next step's stale tree uses it ----
        K0 = *(const float4*)(frow + 0);
        K1 = *(const float4*)(frow + 4);
        K2 = *(const float4*)(frow + 8);
        K3 = *(const float4*)(frow + 12);
        asm volatile("" ::: "memory");

        // ---- 6. remaining relax writes (next step's reads are issued later: in-order safe) ----
        if (rel) {
            g_s[nb] = g2;
            par_s[nb] = (unsigned short)sel;
        }

        // ---- 7. fresh-key reduce over this step's relaxes (lanes 0-7) ----
        float cand = rel ? fnew : INFF;
        float m8 = grp8_min_f32(cand);
        const unsigned fbits = (unsigned)__builtin_amdgcn_readlane(__float_as_int(m8), 0);
        const ull fball = __ballot(rel && (__float_as_uint(cand) == fbits));

        // ---- 8. merge: min over (stale-second-best, fresh keys), tie -> lowest cell ----
        unsigned selnext = scell;
        if (fball) {
            int fl = (int)__builtin_ctzll(fball);     // lowest lane = lowest cell among fresh ties
            unsigned fidx = (unsigned)__builtin_amdgcn_readlane(nb, fl);
            if (fbits < sbits || (fbits == sbits && fidx < scell)) selnext = fidx;
        }

        if (solved) break;   // relax of the solved step already applied (matches reference)
        sel = (int)selnext;
    }

    float* out_hist = out + b * SS;
    float* out_path = out + BATCH * SS + b * SS;
    float* out_g    = out + 2 * BATCH * SS + b * SS;
    for (int i = 0; i < 16; ++i) {
        int c = i * 64 + lane;
        unsigned fbv = __float_as_uint(fop[(c >> 4) * LSTR + (c & 15)]);
        out_hist[c] = (fbv == CLOSEDB) ? 1.0f : 0.0f;
        out_g[c]    = g_s[c];
        out_path[c] = (c == goal_idx) ? 1.0f : 0.0f;
    }
    __syncthreads();   // drain stores before backtrack overwrites
    if (lane == 0) {
        int loc = par_s[goal_idx];
        for (int it = 0; it < NSTEPS; ++it) {
            out_path[loc] = 1.0f;
            if (loc == goal_idx) break;   // parent chain strictly decreasing in expansion time
            loc = par_s[loc];
        }
    }
}

extern "C" void kernel_launch(void* const* d_in, const int* in_sizes, int n_in,
                              void* d_out, int out_size, void* d_ws, size_t ws_size,
                              hipStream_t stream)
{
    // d_in: [0]=cost_maps (unused in 'default' mode), [1]=start, [2]=goal, [3]=obstacles
    const float* start_maps = (const float*)d_in[1];
    const float* goal_maps  = (const float*)d_in[2];
    const float* obst_maps  = (const float*)d_in[3];
    float* out = (float*)d_out;
    hipLaunchKernelGGL(astar_kernel, dim3(BATCH), dim3(64), 0, stream,
                       start_maps, goal_maps, obst_maps, out);
}

// Round 11
// 35.987 us; speedup vs baseline: 1.4632x; 1.4571x over previous
//
#include <hip/hip_runtime.h>

#define BATCH 32
#define SS 1024
#define NSTEPS 972
#define LSTR 20                     // floats per lane row: 16 data + 4 pad = 80B (16B-aligned, 8-way bank spread)

#define UNVIS   0x7F000000u         // huge finite float sentinels: UNVIS < CLOSED < OBST, all > any real f
#define CLOSEDB 0x7F000001u
#define OBSTB   0x7F000002u

typedef unsigned long long ull;

template <int CTRL>
__device__ __forceinline__ int dpp32(int v) {
    return __builtin_amdgcn_update_dpp(v, v, CTRL, 0xF, 0xF, false);
}

// 64-lane f32 min, result (bit-exact copy of some input) broadcast from lane 63.
__device__ __forceinline__ float wave_min_f32_bcast(float v) {
    float t;
    t = __int_as_float(dpp32<0xB1 >(__float_as_int(v))); v = fminf(v, t);  // quad xor1
    t = __int_as_float(dpp32<0x4E >(__float_as_int(v))); v = fminf(v, t);  // quad xor2
    t = __int_as_float(dpp32<0x141>(__float_as_int(v))); v = fminf(v, t);  // row_half_mirror
    t = __int_as_float(dpp32<0x140>(__float_as_int(v))); v = fminf(v, t);  // row_mirror
    t = __int_as_float(dpp32<0x142>(__float_as_int(v))); v = fminf(v, t);  // row_bcast15
    t = __int_as_float(dpp32<0x143>(__float_as_int(v))); v = fminf(v, t);  // row_bcast31
    return __int_as_float(__builtin_amdgcn_readlane(__float_as_int(v), 63));
}

__device__ __forceinline__ unsigned umin2(unsigned a, unsigned b) { return a < b ? a : b; }
__device__ __forceinline__ unsigned slotc(float v, unsigned lm, unsigned i) {
    return (__float_as_uint(v) == lm) ? i : 63u;   // lane-local slot candidate
}

__global__ __launch_bounds__(64)
void astar_kernel(const float* __restrict__ start_maps,
                  const float* __restrict__ goal_maps,
                  const float* __restrict__ obst_maps,
                  float* __restrict__ out)
{
    const int b = blockIdx.x;
    const int lane = threadIdx.x;

    __shared__ __align__(16) float fop[64 * LSTR];   // padded: cell c at (c>>4)*LSTR + (c&15)
    __shared__ __align__(16) float g_s[SS];
    __shared__ unsigned short par_s[SS];
    __shared__ int sh_start, sh_goal;

    const float* st = start_maps + b * SS;
    const float* gl = goal_maps + b * SS;
    const float* ob = obst_maps + b * SS;

    for (int i = 0; i < 16; ++i) {
        int c = i * 64 + lane;
        if (st[c] > 0.5f) sh_start = c;
        if (gl[c] > 0.5f) sh_goal = c;
    }
    __syncthreads();
    const int start_idx = sh_start;
    const int goal_idx = sh_goal;
    const float gi = (float)(goal_idx >> 5);
    const float gj = (float)(goal_idx & 31);
    const float SQRT2F = 1.41421356237309515f;   // fl32(sqrt(2))
    const float WH = 0.501f;
    const float INFF = __int_as_float(0x7f800000);
    const float CB = __uint_as_float(CLOSEDB);

    for (int i = 0; i < 16; ++i) {
        int c = i * 64 + lane;
        g_s[c] = 0.0f;
        par_s[c] = (unsigned short)goal_idx;
        fop[(c >> 4) * LSTR + (c & 15)] = __uint_as_float(ob[c] > 0.5f ? UNVIS : OBSTB);
    }
    __syncthreads();
    if (lane == 0) {
        // f(start) = fl(0.5*0 + fl(0.501*h)) = fh, computed with init-identical op order
        float dx0 = fabsf((float)(start_idx >> 5) - gi);
        float dy0 = fabsf((float)(start_idx & 31) - gj);
        float h0 = __fadd_rn(__fmul_rn(fminf(dx0, dy0), SQRT2F), fabsf(dx0 - dy0));
        fop[(start_idx >> 4) * LSTR + (start_idx & 15)] = __fmul_rn(WH, h0);
    }
    __syncthreads();

    const float* frow = &fop[lane * LSTR];
    int sel = start_idx;             // first selection is trivially the start cell

    #pragma unroll 1
    for (int step = 0; step < NSTEPS; ++step) {
        const bool solved = (sel == goal_idx);
        const int si = sel >> 5, sj = sel & 31;

        // ---- 1. close sel (neighbors never alias sel) ----
        if (lane == 0)
            fop[(sel >> 4) * LSTR + (sel & 15)] = CB;
        asm volatile("" ::: "memory");

        // ---- 2. relax input reads (issued FIRST -> counted wait covers them early) ----
        int k8 = lane < 8 ? (lane < 4 ? lane : lane + 1) : 4;
        int di = k8 / 3 - 1;
        int dj = k8 - (k8 / 3) * 3 - 1;
        int ni = si + di, nj = sj + dj;
        bool act = (lane < 8) && ((unsigned)ni < 32u) && ((unsigned)nj < 32u);
        int nb = act ? ni * 32 + nj : sel;
        int fa = (nb >> 4) * LSTR + (nb & 15);
        unsigned fbv = __float_as_uint(fop[fa]);   // dummy lanes read sel -> CLOSED -> rel=false
        float gnb = g_s[nb];
        float gsel = g_s[sel];

        // ---- 3. scan loads: AFTER close (sees it), BEFORE relax writes (stale wrt them) ----
        float4 r0 = *(const float4*)(frow + 0);
        float4 r1 = *(const float4*)(frow + 4);
        float4 r2 = *(const float4*)(frow + 8);
        float4 r3 = *(const float4*)(frow + 12);
        asm volatile("" ::: "memory");

        // ---- 4. fh arithmetic (no load; bit-identical op order to reference) ----
        float dxn = fabsf((float)ni - gi);
        float dyn = fabsf((float)nj - gj);
        float hn  = __fadd_rn(__fmul_rn(fminf(dxn, dyn), SQRT2F), fabsf(dxn - dyn));
        float fhn = __fmul_rn(WH, hn);

        // ---- 5. relax compute + writes (scan loads above are NOT drained by this wait) ----
        float w = ((di != 0) && (dj != 0)) ? SQRT2F : 1.0f;
        float g2 = __fadd_rn(gsel, w);               // exact: fl(g_sel + w)
        bool rel = act && ((fbv == UNVIS) || (fbv < UNVIS && gnb > g2));
        float fnew = __fadd_rn(__fmul_rn(0.5f, g2), fhn);
        if (rel) {
            fop[fa] = fnew;                          // next iter's scan sees this; this iter's doesn't
            g_s[nb] = g2;
            par_s[nb] = (unsigned short)sel;
        }
        if (solved) break;   // relax of the solved step applied (matches reference); tree skipped

        // ---- 6. tree over stale scan + fresh keys merged in-resolve ----
        float fv = rel ? fnew : INFF;                // fresh candidate (strictly < its stale copy)
        float a0 = fminf(fminf(r0.x, r0.y), fminf(r0.z, r0.w));
        float a1 = fminf(fminf(r1.x, r1.y), fminf(r1.z, r1.w));
        float a2 = fminf(fminf(r2.x, r2.y), fminf(r2.z, r2.w));
        float a3 = fminf(fminf(r3.x, r3.y), fminf(r3.z, r3.w));
        float lmin = fminf(fminf(a0, a1), fminf(a2, a3));
        const unsigned lm = __float_as_uint(lmin);
        unsigned s0 = umin2(umin2(slotc(r0.x, lm, 0),  slotc(r0.y, lm, 1)),
                            umin2(slotc(r0.z, lm, 2),  slotc(r0.w, lm, 3)));
        unsigned s1 = umin2(umin2(slotc(r1.x, lm, 4),  slotc(r1.y, lm, 5)),
                            umin2(slotc(r1.z, lm, 6),  slotc(r1.w, lm, 7)));
        unsigned s2 = umin2(umin2(slotc(r2.x, lm, 8),  slotc(r2.y, lm, 9)),
                            umin2(slotc(r2.z, lm, 10), slotc(r2.w, lm, 11)));
        unsigned s3 = umin2(umin2(slotc(r3.x, lm, 12), slotc(r3.y, lm, 13)),
                            umin2(slotc(r3.z, lm, 14), slotc(r3.w, lm, 15)));
        unsigned slot = umin2(umin2(s0, s1), umin2(s2, s3));

        const float gmin = wave_min_f32_bcast(fminf(lmin, fv));
        const unsigned gb = __float_as_uint(gmin);
        const ull bal_s = __ballot(lm == gb);                       // stale matches
        const ull bal_f = __ballot(__float_as_uint(fv) == gb);      // fresh matches (INF never matches)

        unsigned idx_s = 0xFFFFu, idx_f = 0xFFFFu;
        if (bal_s) {            // uniform branch (SGPR)
            int owner = (int)__builtin_ctzll(bal_s);                // lowest lane = lowest cell block
            idx_s = (unsigned)(owner * 16 + __builtin_amdgcn_readlane((int)slot, owner));
        }
        if (bal_f) {            // fresh lanes are nb-ascending -> ctz = lowest fresh cell
            int fl = (int)__builtin_ctzll(bal_f);
            idx_f = (unsigned)__builtin_amdgcn_readlane(nb, fl);
        }
        sel = (int)umin2(idx_s, idx_f);   // equal values -> lowest flat index (exact tie-break)
    }

    float* out_hist = out + b * SS;
    float* out_path = out + BATCH * SS + b * SS;
    float* out_g    = out + 2 * BATCH * SS + b * SS;
    for (int i = 0; i < 16; ++i) {
        int c = i * 64 + lane;
        unsigned fbv = __float_as_uint(fop[(c >> 4) * LSTR + (c & 15)]);
        out_hist[c] = (fbv == CLOSEDB) ? 1.0f : 0.0f;
        out_g[c]    = g_s[c];
        out_path[c] = (c == goal_idx) ? 1.0f : 0.0f;
    }
    __syncthreads();   // drain stores before backtrack overwrites
    if (lane == 0) {
        int loc = par_s[goal_idx];
        for (int it = 0; it < NSTEPS; ++it) {
            out_path[loc] = 1.0f;
            if (loc == goal_idx) break;   // parent chain strictly decreasing in expansion time
            loc = par_s[loc];
        }
    }
}

extern "C" void kernel_launch(void* const* d_in, const int* in_sizes, int n_in,
                              void* d_out, int out_size, void* d_ws, size_t ws_size,
                              hipStream_t stream)
{
    // d_in: [0]=cost_maps (unused in 'default' mode), [1]=start, [2]=goal, [3]=obstacles
    const float* start_maps = (const float*)d_in[1];
    const float* goal_maps  = (const float*)d_in[2];
    const float* obst_maps  = (const float*)d_in[3];
    float* out = (float*)d_out;
    hipLaunchKernelGGL(astar_kernel, dim3(BATCH), dim3(64), 0, stream,
                       start_maps, goal_maps, obst_maps, out);
}